// Round 5
// baseline (1509.015 us; speedup 1.0000x reference)
//
#include <hip/hip_runtime.h>

#define LOG2PI 1.837877f
#define NLAB 46
#define KK 4
#define LSEQ 512
#define KC 184            // KK*NLAB
#define BLOCK 768         // 12 waves: 3 per SIMD, balanced
#define NA 736            // 46 parents * 16 lanes; threads 736..767 = emission

__device__ __forceinline__ float fastrcp(float x){ return __builtin_amdgcn_rcpf(x); }
__device__ __forceinline__ unsigned umx(unsigned a, unsigned b){ return a > b ? a : b; }
__device__ __forceinline__ unsigned umn(unsigned a, unsigned b){ return a < b ? a : b; }
__device__ __forceinline__ unsigned umed3(unsigned a, unsigned b, unsigned c){
    unsigned d;
    asm("v_med3_u32 %0, %1, %2, %3" : "=v"(d) : "v"(a), "v"(b), "v"(c));
    return d;
}
template<int CTRL>
__device__ __forceinline__ unsigned dppq(unsigned v){   // quad_perm exchange (VALU pipe)
    return (unsigned)__builtin_amdgcn_mov_dpp((int)v, CTRL, 0xF, 0xF, false);
}
template<int OFF>
__device__ __forceinline__ unsigned swz(unsigned v){    // ds_swizzle xor (LDS pipe)
    return (unsigned)__builtin_amdgcn_ds_swizzle((int)v, OFF);
}
template<int N> struct IC { static constexpr int value = N; };

__global__ __launch_bounds__(BLOCK) void lveg_kernel(
    const int* __restrict__ tokens,
    const float* __restrict__ s_w_tab,
    const float* __restrict__ s_m_tab,
    const float* __restrict__ s_v_tab,
    const float* __restrict__ t_weight,
    const float* __restrict__ t_mu,
    const float* __restrict__ t_var_p,
    float* __restrict__ out)
{
    // hot arrays first (small immediate LDS offsets)
    __shared__ float4 lam2v[2][NLAB];    // carry lam2, transposed: [c] = {k0..k3}
    __shared__ float4 glamv[2][NLAB];    // carry mu*lam2
    __shared__ float4 z2sv[2][NLAB];     // carry sc + z2
    __shared__ float  scv[KK*NLAB];      // raw carry scores (final logsumexp)
    __shared__ float4 emi[2][NLAB];      // emission: sw, 1/sv, sm/sv, z2
    __shared__ int    tokL[LSEQ];
    __shared__ float4 tabA[NLAB*NLAB];   // per-(c,p): e0, e1, invDetS, l11
    __shared__ float2 tabB[NLAB*NLAB];   // per-(c,p): l01, A(=zeta1+LOG2PI+tw)

    const int b = blockIdx.x;
    const int tid = threadIdx.x;
    const int s = tid & 15;              // lane within 16-lane parent group
    const int p = tid >> 4;              // parent label 0..47
    const bool isA = (p < NLAB);
    const unsigned vmask2 = (s < 14) ? 0xFFFFFFFFu : 0u;   // ci=2 validity
    const int c2 = (s < 14) ? (s + 32) : 0;                // clamped ci=2 child

    // ---- one-time: phase-C constant tables into LDS + token preload ----
    for (int cp = tid; cp < NLAB*NLAB; cp += BLOCK) {
        float v0 = t_var_p[cp*3+0], v1 = t_var_p[cp*3+1], v2 = t_var_p[cp*3+2];
        float tm0 = t_mu[cp*2+0],  tm1 = t_mu[cp*2+1];
        float S00 = v0*v0 + v1*v1, S01 = v1*v2, S11 = v2*v2;
        float det = S00*S11 - S01*S01;
        float inv = 1.0f / det;
        float l00 = S11*inv, l01 = -S01*inv, l11 = S00*inv;
        float e0 = l00*tm0 + l01*tm1;
        float e1 = l01*tm0 + l11*tm1;
        float q1 = e0*(S00*e0 + S01*e1) + e1*(S01*e0 + S11*e1);
        float zeta1 = -0.5f*(2.0f*LOG2PI + __logf(det) + q1);
        tabA[cp] = make_float4(e0, e1, inv, l11);
        tabB[cp] = make_float2(l01, zeta1 + LOG2PI + t_weight[cp]);
    }
    for (int i = tid; i < LSEQ; i += BLOCK) tokL[i] = tokens[b*LSEQ + i];

    // ---- one-time: phase-A per-(c,p) constants in registers ----
    float rce0[3], rl11[3], rqb[3], rqc[3], rqe[3], rinv[3], rA[3];
    if (isA) {
#pragma unroll
        for (int ci = 0; ci < 3; ++ci) {
            int c = s + 16*ci;
            if (c < NLAB) {
                int cp = c*NLAB + p;
                float v0 = t_var_p[cp*3+0], v1 = t_var_p[cp*3+1], v2 = t_var_p[cp*3+2];
                float tm0 = t_mu[cp*2+0],  tm1 = t_mu[cp*2+1];
                float S00 = v0*v0 + v1*v1, S01 = v1*v2, S11 = v2*v2;
                float det = S00*S11 - S01*S01;
                float inv = 1.0f / det;
                float l00 = S11*inv, l01 = -S01*inv, l11 = S00*inv;
                float e0 = l00*tm0 + l01*tm1;
                float e1 = l01*tm0 + l11*tm1;
                float q1 = e0*(S00*e0 + S01*e1) + e1*(S01*e0 + S11*e1);
                float zeta1 = -0.5f*(2.0f*LOG2PI + __logf(det) + q1);
                rce0[ci] = e0;
                rl11[ci] = l11;
                rqb[ci]  = 2.0f*l01*e1;
                rqc[ci]  = l00*e1*e1;
                rqe[ci]  = e1*e1;
                rinv[ci] = inv;
                rA[ci]   = zeta1 + LOG2PI + t_weight[cp];
            } else {
                rce0[ci]=0.f; rl11[ci]=0.f; rqb[ci]=0.f; rqc[ci]=0.f;
                rqe[ci]=0.f; rinv[ci]=1.f; rA[ci]=0.f;
            }
        }
    }

    // ---- carry init from emission at position 0 (transposed layout) ----
    if (tid < NLAB) {
        int tok0 = tokens[b * LSEQ];
        float sw  = s_w_tab[tok0*NLAB + tid];
        float sm  = s_m_tab[tok0*NLAB + tid];
        float svr = s_v_tab[tok0*NLAB + tid];
        float gv = svr*svr;
        float lam2 = 1.0f / gv;
        float glam = sm * lam2;
        float z2 = -0.5f*(LOG2PI + __logf(gv) + sm*glam);
        float zpad = -1e30f - 0.5f*LOG2PI;
        lam2v[0][tid] = make_float4(lam2, 1.0f, 1.0f, 1.0f);
        glamv[0][tid] = make_float4(glam, 0.0f, 0.0f, 0.0f);
        z2sv[0][tid]  = make_float4(sw + z2, zpad, zpad, zpad);
    }
    // ---- emission prefetch for t=1 (tail threads) ----
    if (tid >= NA) {
        int el = tid - NA;
        int tok = tokens[b*LSEQ + 1];
#pragma unroll
        for (int rep = 0; rep < 2; ++rep) {
            int pe = el + 32*rep;
            if (pe < NLAB) {
                float sw  = s_w_tab[tok*NLAB + pe];
                float sm  = s_m_tab[tok*NLAB + pe];
                float svr = s_v_tab[tok*NLAB + pe];
                float sv = svr*svr;
                float rs = 1.0f / sv;
                float eb = sm * rs;
                float ez = -0.5f*(LOG2PI + __logf(sv) + sm*eb);
                emi[1][pe] = make_float4(sw, rs, eb, ez);
            }
        }
    }
    __syncthreads();

    // ================= the scan: 1 barrier per step =================
    auto stepf = [&](auto CC, int t) {
        constexpr int CUR = decltype(CC)::value;
        if (isA) {
            // ---- upfront carry loads (9 x ds_read_b128), pinned before compute ----
            float4 L0 = lam2v[CUR][s],      G0 = glamv[CUR][s],      Z0 = z2sv[CUR][s];
            float4 L1 = lam2v[CUR][s + 16], G1 = glamv[CUR][s + 16], Z1 = z2sv[CUR][s + 16];
            float4 L2 = lam2v[CUR][c2],     G2 = glamv[CUR][c2],     Z2 = z2sv[CUR][c2];
            __builtin_amdgcn_sched_barrier(0);
            unsigned t0=0u, t1=0u, t2=0u, t3=0u;
#define CAND(ci, k, lam2, glam, z2s) {                                        \
            float em0 = rce0[ci] + (glam);                                    \
            float dm  = fmaf((lam2), rl11[ci], rinv[ci]);                     \
            float Q   = fmaf(em0, fmaf(rl11[ci], em0, -rqb[ci]),              \
                             fmaf((lam2), rqe[ci], rqc[ci]));                 \
            float sc  = fmaf(0.5f, fmaf(Q, fastrcp(dm), -__logf(dm)),         \
                             rA[ci] + (z2s));                                 \
            unsigned u = __float_as_uint(sc);                                 \
            unsigned key = u ^ (((unsigned)((int)u >> 31)) | 0x80000000u);    \
            unsigned pk = (key & 0xFFFFFF00u) | (unsigned)((k)*NLAB + s + 16*(ci)); \
            if ((ci) == 2) pk &= vmask2;                                      \
            unsigned n0 = umx(t0, pk);                                        \
            unsigned n1 = umed3(pk, t0, t1);                                  \
            unsigned n2 = umed3(pk, t1, t2);                                  \
            unsigned n3 = umed3(pk, t2, t3);                                  \
            t0=n0; t1=n1; t2=n2; t3=n3; }
            CAND(0, 0, L0.x, G0.x, Z0.x)  CAND(0, 1, L0.y, G0.y, Z0.y)
            CAND(0, 2, L0.z, G0.z, Z0.z)  CAND(0, 3, L0.w, G0.w, Z0.w)
            CAND(1, 0, L1.x, G1.x, Z1.x)  CAND(1, 1, L1.y, G1.y, Z1.y)
            CAND(1, 2, L1.z, G1.z, Z1.z)  CAND(1, 3, L1.w, G1.w, Z1.w)
            CAND(2, 0, L2.x, G2.x, Z2.x)  CAND(2, 1, L2.y, G2.y, Z2.y)
            CAND(2, 2, L2.z, G2.z, Z2.z)  CAND(2, 3, L2.w, G2.w, Z2.w)
#undef CAND
            // ---- merge across 16-lane group: DPP (m=1,2) + swizzle (m=4,8) ----
#define MSTAGE(F) { unsigned b0=F(t0), b1=F(t1), b2=F(t2), b3=F(t3);              \
                unsigned L0m=umx(t0,b3), L1m=umx(t1,b2), L2m=umx(t2,b1), L3m=umx(t3,b0); \
                unsigned x;                                                       \
                x=umx(L0m,L2m); L2m=umn(L0m,L2m); L0m=x;  x=umx(L1m,L3m); L3m=umn(L1m,L3m); L1m=x; \
                x=umx(L0m,L1m); L1m=umn(L0m,L1m); L0m=x;  x=umx(L2m,L3m); L3m=umn(L2m,L3m); L2m=x; \
                t0=L0m; t1=L1m; t2=L2m; t3=L3m; }
            MSTAGE(dppq<0xB1>)      // xor 1
            MSTAGE(dppq<0x4E>)      // xor 2
            MSTAGE(swz<0x101F>)     // xor 4
            {   // final stage (xor 8): set-only
                unsigned b0=swz<0x201F>(t0), b1=swz<0x201F>(t1),
                         b2=swz<0x201F>(t2), b3=swz<0x201F>(t3);
                unsigned L0m=umx(t0,b3), L1m=umx(t1,b2), L2m=umx(t2,b1), L3m=umx(t3,b0);
                t0=L0m; t1=L1m; t2=L2m; t3=L3m;
            }
#undef MSTAGE
            // ---- phase C: lanes s<4 recompute survivor s exactly + emission ----
            if (s < 4) {
                unsigned sel = (s==0)?t0 : (s==1)?t1 : (s==2)?t2 : t3;
                unsigned kc = sel & 0xFFu;
                unsigned k  = (kc * 1428u) >> 16;
                int c  = (int)kc - (int)k*NLAB;
                int cp = c*NLAB + p;
                float4 ta = tabA[cp];                 // e0,e1,inv,l11
                float2 tb = tabB[cp];                 // l01, A
                float lam2 = ((const float*)&lam2v[CUR][0])[4*c + (int)k];
                float glam = ((const float*)&glamv[CUR][0])[4*c + (int)k];
                float z2s  = ((const float*)&z2sv[CUR][0])[4*c + (int)k];
                float em0 = ta.x + glam;
                float em1 = ta.y;
                float l01 = tb.x;
                float l00 = fmaf(l01, l01, ta.z) * fastrcp(ta.w);  // (inv+l01^2)/l11
                float dm  = fmaf(lam2, ta.w, ta.z);
                float rdm = fastrcp(dm);
                float lm00 = l00 + lam2;
                float Q = fmaf(em0, fmaf(ta.w, em0, -2.0f*l01*em1), lm00*em1*em1);
                float score = fmaf(0.5f, fmaf(Q, rdm, -__logf(dm)), tb.y + z2s);
                float mu2  = rdm*(lm00*em1 - l01*em0);
                float var2 = lm00*rdm;
                float4 ev = emi[CUR ^ 1][p];
                float rv1 = fastrcp(var2);
                float lam = rv1 + ev.y;
                float emm = fmaf(mu2, rv1, ev.z);
                float vm  = fastrcp(lam);
                float z1 = -0.5f*(LOG2PI + __logf(var2) + mu2*mu2*rv1);
                float zm = -0.5f*(LOG2PI + __logf(vm) + emm*emm*vm);
                float nsc = score + (z1 + ev.w - zm) + ev.x;
                ((float*)&lam2v[CUR^1][p])[s] = lam;
                ((float*)&glamv[CUR^1][p])[s] = emm;
                ((float*)&z2sv[CUR^1][p])[s]  = nsc + zm;
                scv[(int)s*NLAB + p] = nsc;
            }
        } else {
            // ---- emission prefetch for step t+1 into emi[CUR] (32 tail threads) ----
            if (t + 1 < LSEQ) {
                int el = tid - NA;
                int tok = tokL[t + 1];
#pragma unroll
                for (int rep = 0; rep < 2; ++rep) {
                    int pe = el + 32*rep;
                    if (pe < NLAB) {
                        float sw  = s_w_tab[tok*NLAB + pe];
                        float sm  = s_m_tab[tok*NLAB + pe];
                        float svr = s_v_tab[tok*NLAB + pe];
                        float sv = svr*svr;
                        float rs = 1.0f / sv;
                        float eb = sm * rs;
                        float ez = -0.5f*(LOG2PI + __logf(sv) + sm*eb);
                        emi[CUR][pe] = make_float4(sw, rs, eb, ez);
                    }
                }
            }
        }
        __syncthreads();   // the ONLY barrier per step
    };

    int t = 1;
#pragma unroll 1
    for (int it = 0; it < (LSEQ - 2) / 2; ++it) {   // 255 double-steps: t=1..510
        stepf(IC<0>{}, t); ++t;
        stepf(IC<1>{}, t); ++t;
    }
    stepf(IC<0>{}, t);   // t = 511

    // ---- final logsumexp over 184 component scores (wave 0) ----
    if (tid < 64) {
        float mx = -1e38f;
        for (int i = tid; i < KC; i += 64) mx = fmaxf(mx, scv[i]);
#pragma unroll
        for (int m = 32; m; m >>= 1) mx = fmaxf(mx, __shfl_xor(mx, m, 64));
        float sum = 0.0f;
        for (int i = tid; i < KC; i += 64) sum += __expf(scv[i] - mx);
#pragma unroll
        for (int m = 32; m; m >>= 1) sum += __shfl_xor(sum, m, 64);
        if (tid == 0) out[b] = mx + __logf(sum);
    }
}

extern "C" void kernel_launch(void* const* d_in, const int* in_sizes, int n_in,
                              void* d_out, int out_size, void* d_ws, size_t ws_size,
                              hipStream_t stream) {
    const int*   tokens = (const int*)d_in[0];
    const float* sw     = (const float*)d_in[1];
    const float* sm     = (const float*)d_in[2];
    const float* sv     = (const float*)d_in[3];
    const float* tw     = (const float*)d_in[4];
    const float* tmu    = (const float*)d_in[5];
    const float* tvp    = (const float*)d_in[6];
    float* o = (float*)d_out;
    hipLaunchKernelGGL(lveg_kernel, dim3(64), dim3(BLOCK), 0, stream,
                       tokens, sw, sm, sv, tw, tmu, tvp, o);
}

// Round 6
// 1182.228 us; speedup vs baseline: 1.2764x; 1.2764x over previous
//
#include <hip/hip_runtime.h>

#define LOG2PI 1.837877f
#define LN2 0.6931471805599453f
#define RLN2 1.4426950408889634f
#define NLAB 46
#define KK 4
#define LSEQ 512
#define KC 184            // KK*NLAB
#define BLOCK 832         // 13 waves: 12 A-waves (wave 11 half) + light emission wave 12
#define NA 736            // 46 parents * 16 lanes
#define EMB 768           // emission wave start

__device__ __forceinline__ float fastrcp(float x){ return __builtin_amdgcn_rcpf(x); }
__device__ __forceinline__ float flog2(float x){ return __builtin_amdgcn_logf(x); }
__device__ __forceinline__ float fmed3(float a, float b, float c){
    return __builtin_amdgcn_fmed3f(a, b, c);
}
template<int CTRL>
__device__ __forceinline__ float dppq(float v){   // quad_perm exchange (VALU pipe)
    return __uint_as_float((unsigned)__builtin_amdgcn_mov_dpp(
        (int)__float_as_uint(v), CTRL, 0xF, 0xF, false));
}
template<int OFF>
__device__ __forceinline__ float swz(float v){    // ds_swizzle xor (LDS pipe)
    return __uint_as_float((unsigned)__builtin_amdgcn_ds_swizzle(
        (int)__float_as_uint(v), OFF));
}
template<int N> struct IC { static constexpr int value = N; };

__global__ __launch_bounds__(BLOCK, 4) void lveg_kernel(
    const int* __restrict__ tokens,
    const float* __restrict__ s_w_tab,
    const float* __restrict__ s_m_tab,
    const float* __restrict__ s_v_tab,
    const float* __restrict__ t_weight,
    const float* __restrict__ t_mu,
    const float* __restrict__ t_var_p,
    float* __restrict__ out)
{
    // hot arrays first (small immediate LDS offsets)
    __shared__ float4 lam2v[2][NLAB];    // carry lam2, transposed: [c] = {k0..k3}
    __shared__ float4 glamv[2][NLAB];    // carry mu*lam2
    __shared__ float4 z2sv[2][NLAB];     // carry (sc + z2) * RLN2  (selection-scaled)
    __shared__ float  scv[KC];           // raw carry scores (final logsumexp)
    __shared__ float4 emi[2][NLAB];      // emission: sw, 1/sv, sm/sv, z2
    __shared__ int    tokL[LSEQ];
    __shared__ float4 tabA[NLAB*NLAB];   // per-(c,p): e0, e1, invDetS, l11
    __shared__ float2 tabB[NLAB*NLAB];   // per-(c,p): l01, A(=zeta1+LOG2PI+tw)

    const int b = blockIdx.x;
    const int tid = threadIdx.x;
    const int s = tid & 15;              // lane within 16-lane parent group
    const int p = tid >> 4;              // parent label 0..51
    const bool isA = (p < NLAB);
    const unsigned vmask2 = (s < 14) ? 0xFFFFFFFFu : 0u;       // ci=2 validity
    const unsigned vorm2  = (s < 14) ? 0u : 0xFF800000u;       // -inf for tail lanes
    const int c2 = (s < 14) ? (s + 32) : 0;                    // clamped ci=2 child
    const float NEGINF = __uint_as_float(0xFF800000u);

    // ---- one-time: phase-C constant tables into LDS + token preload ----
    for (int cp = tid; cp < NLAB*NLAB; cp += BLOCK) {
        float v0 = t_var_p[cp*3+0], v1 = t_var_p[cp*3+1], v2 = t_var_p[cp*3+2];
        float tm0 = t_mu[cp*2+0],  tm1 = t_mu[cp*2+1];
        float S00 = v0*v0 + v1*v1, S01 = v1*v2, S11 = v2*v2;
        float det = S00*S11 - S01*S01;
        float inv = 1.0f / det;
        float l00 = S11*inv, l01 = -S01*inv, l11 = S00*inv;
        float e0 = l00*tm0 + l01*tm1;
        float e1 = l01*tm0 + l11*tm1;
        float q1 = e0*(S00*e0 + S01*e1) + e1*(S01*e0 + S11*e1);
        float zeta1 = -0.5f*(2.0f*LOG2PI + __logf(det) + q1);
        tabA[cp] = make_float4(e0, e1, inv, l11);
        tabB[cp] = make_float2(l01, zeta1 + LOG2PI + t_weight[cp]);
    }
    for (int i = tid; i < LSEQ; i += BLOCK) tokL[i] = tokens[b*LSEQ + i];

    // ---- one-time: phase-A per-(c,p) constants in registers ----
    // selection key is the true score scaled by 1/ln2 (monotone): lets us use raw
    // v_log_f32 (log2) and skip the ln2 fixup per candidate.
    float rce0[3], rl11[3], rinv[3], rl11s[3], rqbs[3], rqes[3], rqcs[3], rAs[3];
    if (isA) {
#pragma unroll
        for (int ci = 0; ci < 3; ++ci) {
            int c = s + 16*ci;
            if (c < NLAB) {
                int cp = c*NLAB + p;
                float v0 = t_var_p[cp*3+0], v1 = t_var_p[cp*3+1], v2 = t_var_p[cp*3+2];
                float tm0 = t_mu[cp*2+0],  tm1 = t_mu[cp*2+1];
                float S00 = v0*v0 + v1*v1, S01 = v1*v2, S11 = v2*v2;
                float det = S00*S11 - S01*S01;
                float inv = 1.0f / det;
                float l00 = S11*inv, l01 = -S01*inv, l11 = S00*inv;
                float e0 = l00*tm0 + l01*tm1;
                float e1 = l01*tm0 + l11*tm1;
                float q1 = e0*(S00*e0 + S01*e1) + e1*(S01*e0 + S11*e1);
                float zeta1 = -0.5f*(2.0f*LOG2PI + __logf(det) + q1);
                rce0[ci]  = e0;
                rl11[ci]  = l11;
                rinv[ci]  = inv;
                rl11s[ci] = l11 * RLN2;
                rqbs[ci]  = 2.0f*l01*e1 * RLN2;
                rqes[ci]  = e1*e1 * RLN2;
                rqcs[ci]  = l00*e1*e1 * RLN2;
                rAs[ci]   = (zeta1 + LOG2PI + t_weight[cp]) * RLN2;
            } else {
                rce0[ci]=0.f; rl11[ci]=0.f; rinv[ci]=1.f; rl11s[ci]=0.f;
                rqbs[ci]=0.f; rqes[ci]=0.f; rqcs[ci]=0.f; rAs[ci]=0.f;
            }
        }
    }

    // ---- carry init from emission at position 0 (transposed layout) ----
    if (tid < NLAB) {
        int tok0 = tokens[b * LSEQ];
        float sw  = s_w_tab[tok0*NLAB + tid];
        float sm  = s_m_tab[tok0*NLAB + tid];
        float svr = s_v_tab[tok0*NLAB + tid];
        float gv = svr*svr;
        float lam2 = 1.0f / gv;
        float glam = sm * lam2;
        float z2 = -0.5f*(LOG2PI + __logf(gv) + sm*glam);
        float zpad = (-1e30f - 0.5f*LOG2PI) * RLN2;
        lam2v[0][tid] = make_float4(lam2, 1.0f, 1.0f, 1.0f);
        glamv[0][tid] = make_float4(glam, 0.0f, 0.0f, 0.0f);
        z2sv[0][tid]  = make_float4((sw + z2) * RLN2, zpad, zpad, zpad);
    }
    // ---- emission prefetch for t=1 (dedicated wave 12) ----
    if (tid >= EMB) {
        int pe = tid - EMB;
        if (pe < NLAB) {
            int tok = tokens[b*LSEQ + 1];
            float sw  = s_w_tab[tok*NLAB + pe];
            float sm  = s_m_tab[tok*NLAB + pe];
            float svr = s_v_tab[tok*NLAB + pe];
            float sv = svr*svr;
            float rs = 1.0f / sv;
            float eb = sm * rs;
            float ez = -0.5f*(LOG2PI + __logf(sv) + sm*eb);
            emi[1][pe] = make_float4(sw, rs, eb, ez);
        }
    }
    __syncthreads();

    // ================= the scan: 1 barrier per step =================
    auto stepf = [&](auto CC, int t) {
        constexpr int CUR = decltype(CC)::value;
        if (isA) {
            // ---- upfront carry loads (9 x ds_read_b128), pinned before compute ----
            float4 L0 = lam2v[CUR][s],      G0 = glamv[CUR][s],      Z0 = z2sv[CUR][s];
            float4 L1 = lam2v[CUR][s + 16], G1 = glamv[CUR][s + 16], Z1 = z2sv[CUR][s + 16];
            float4 L2 = lam2v[CUR][c2],     G2 = glamv[CUR][c2],     Z2 = z2sv[CUR][c2];
            __builtin_amdgcn_sched_barrier(0);
            float t0=NEGINF, t1=NEGINF, t2=NEGINF, t3=NEGINF;
#define CAND(ci, k, lam2, glam, z2s) {                                        \
            float em0 = rce0[ci] + (glam);                                    \
            float dm  = fmaf((lam2), rl11[ci], rinv[ci]);                     \
            float tA  = fmaf(rl11s[ci], em0, -rqbs[ci]);                      \
            float tB  = fmaf((lam2), rqes[ci], rqcs[ci]);                     \
            float Q   = fmaf(em0, tA, tB);                                    \
            float key = fmaf(0.5f, fmaf(Q, fastrcp(dm), -flog2(dm)),          \
                             rAs[ci] + (z2s));                                \
            unsigned kb = (__float_as_uint(key) & 0xFFFFFF00u)                \
                        | (unsigned)((k)*NLAB + s + 16*(ci));                 \
            if ((ci) == 2) kb = (kb & vmask2) | vorm2;                        \
            float fk = __uint_as_float(kb);                                   \
            float n0 = fmaxf(t0, fk);                                         \
            float n1 = fmed3(fk, t0, t1);                                     \
            float n2 = fmed3(fk, t1, t2);                                     \
            float n3 = fmed3(fk, t2, t3);                                     \
            t0=n0; t1=n1; t2=n2; t3=n3; }
            CAND(0, 0, L0.x, G0.x, Z0.x)  CAND(0, 1, L0.y, G0.y, Z0.y)
            CAND(0, 2, L0.z, G0.z, Z0.z)  CAND(0, 3, L0.w, G0.w, Z0.w)
            CAND(1, 0, L1.x, G1.x, Z1.x)  CAND(1, 1, L1.y, G1.y, Z1.y)
            CAND(1, 2, L1.z, G1.z, Z1.z)  CAND(1, 3, L1.w, G1.w, Z1.w)
            CAND(2, 0, L2.x, G2.x, Z2.x)  CAND(2, 1, L2.y, G2.y, Z2.y)
            CAND(2, 2, L2.z, G2.z, Z2.z)  CAND(2, 3, L2.w, G2.w, Z2.w)
#undef CAND
            // ---- merge across 16-lane group: DPP (m=1,2) + swizzle (m=4,8) ----
#define MSTAGE(F) { float b0=F(t0), b1=F(t1), b2=F(t2), b3=F(t3);                 \
                float M0=fmaxf(t0,b3), M1=fmaxf(t1,b2), M2=fmaxf(t2,b1), M3=fmaxf(t3,b0); \
                float x;                                                          \
                x=fmaxf(M0,M2); M2=fminf(M0,M2); M0=x;  x=fmaxf(M1,M3); M3=fminf(M1,M3); M1=x; \
                x=fmaxf(M0,M1); M1=fminf(M0,M1); M0=x;  x=fmaxf(M2,M3); M3=fminf(M2,M3); M2=x; \
                t0=M0; t1=M1; t2=M2; t3=M3; }
            MSTAGE(dppq<0xB1>)      // xor 1
            MSTAGE(dppq<0x4E>)      // xor 2
            MSTAGE(swz<0x101F>)     // xor 4
            {   // final stage (xor 8): set-only (lanes 0..3 hold identical sets)
                float b0=swz<0x201F>(t0), b1=swz<0x201F>(t1),
                      b2=swz<0x201F>(t2), b3=swz<0x201F>(t3);
                float M0=fmaxf(t0,b3), M1=fmaxf(t1,b2), M2=fmaxf(t2,b1), M3=fmaxf(t3,b0);
                t0=M0; t1=M1; t2=M2; t3=M3;
            }
#undef MSTAGE
            // ---- phase C: lanes s<4 recompute survivor s exactly + emission ----
            if (s < 4) {
                float sel = (s==0)?t0 : (s==1)?t1 : (s==2)?t2 : t3;
                unsigned kc = __float_as_uint(sel) & 0xFFu;
                unsigned k  = (kc * 1428u) >> 16;
                int c  = (int)kc - (int)k*NLAB;
                int cp = c*NLAB + p;
                float4 ta = tabA[cp];                 // e0,e1,inv,l11
                float2 tb = tabB[cp];                 // l01, A
                float lam2 = ((const float*)&lam2v[CUR][0])[4*c + (int)k];
                float glam = ((const float*)&glamv[CUR][0])[4*c + (int)k];
                float z2s  = ((const float*)&z2sv[CUR][0])[4*c + (int)k] * LN2;
                float em0 = ta.x + glam;
                float em1 = ta.y;
                float l01 = tb.x;
                float l00 = fmaf(l01, l01, ta.z) * fastrcp(ta.w);  // (inv+l01^2)/l11
                float dm  = fmaf(lam2, ta.w, ta.z);
                float rdm = fastrcp(dm);
                float lm00 = l00 + lam2;
                float Q = fmaf(em0, fmaf(ta.w, em0, -2.0f*l01*em1), lm00*em1*em1);
                float score = fmaf(0.5f, fmaf(Q, rdm, -__logf(dm)), tb.y + z2s);
                float mu2  = rdm*(lm00*em1 - l01*em0);
                float var2 = lm00*rdm;
                float4 ev = emi[CUR ^ 1][p];
                float rv1 = fastrcp(var2);
                float lam = rv1 + ev.y;
                float emm = fmaf(mu2, rv1, ev.z);
                float vm  = fastrcp(lam);
                float z1 = -0.5f*(LOG2PI + __logf(var2) + mu2*mu2*rv1);
                float zm = -0.5f*(LOG2PI + __logf(vm) + emm*emm*vm);
                float nsc = score + (z1 + ev.w - zm) + ev.x;
                ((float*)&lam2v[CUR^1][p])[s] = lam;
                ((float*)&glamv[CUR^1][p])[s] = emm;
                ((float*)&z2sv[CUR^1][p])[s]  = (nsc + zm) * RLN2;
                scv[(int)s*NLAB + p] = nsc;
            }
        } else if (tid >= EMB) {
            // ---- emission prefetch for step t+1 into emi[CUR] (wave 12) ----
            int pe = tid - EMB;
            if (pe < NLAB && t + 1 < LSEQ) {
                int tok = tokL[t + 1];
                float sw  = s_w_tab[tok*NLAB + pe];
                float sm  = s_m_tab[tok*NLAB + pe];
                float svr = s_v_tab[tok*NLAB + pe];
                float sv = svr*svr;
                float rs = 1.0f / sv;
                float eb = sm * rs;
                float ez = -0.5f*(LOG2PI + __logf(sv) + sm*eb);
                emi[CUR][pe] = make_float4(sw, rs, eb, ez);
            }
        }
        __syncthreads();   // the ONLY barrier per step
    };

    int t = 1;
#pragma unroll 1
    for (int it = 0; it < (LSEQ - 2) / 2; ++it) {   // 255 double-steps: t=1..510
        stepf(IC<0>{}, t); ++t;
        stepf(IC<1>{}, t); ++t;
    }
    stepf(IC<0>{}, t);   // t = 511

    // ---- final logsumexp over 184 component scores (wave 0) ----
    if (tid < 64) {
        float mx = -1e38f;
        for (int i = tid; i < KC; i += 64) mx = fmaxf(mx, scv[i]);
#pragma unroll
        for (int m = 32; m; m >>= 1) mx = fmaxf(mx, __shfl_xor(mx, m, 64));
        float sum = 0.0f;
        for (int i = tid; i < KC; i += 64) sum += __expf(scv[i] - mx);
#pragma unroll
        for (int m = 32; m; m >>= 1) sum += __shfl_xor(sum, m, 64);
        if (tid == 0) out[b] = mx + __logf(sum);
    }
}

extern "C" void kernel_launch(void* const* d_in, const int* in_sizes, int n_in,
                              void* d_out, int out_size, void* d_ws, size_t ws_size,
                              hipStream_t stream) {
    const int*   tokens = (const int*)d_in[0];
    const float* sw     = (const float*)d_in[1];
    const float* sm     = (const float*)d_in[2];
    const float* sv     = (const float*)d_in[3];
    const float* tw     = (const float*)d_in[4];
    const float* tmu    = (const float*)d_in[5];
    const float* tvp    = (const float*)d_in[6];
    float* o = (float*)d_out;
    hipLaunchKernelGGL(lveg_kernel, dim3(64), dim3(BLOCK), 0, stream,
                       tokens, sw, sm, sv, tw, tmu, tvp, o);
}

// Round 7
// 1137.799 us; speedup vs baseline: 1.3263x; 1.0390x over previous
//
#include <hip/hip_runtime.h>

#define LOG2PI 1.837877f
#define LN2 0.6931471805599453f
#define RLN2 1.4426950408889634f
#define NLAB 46
#define KK 4
#define LSEQ 512
#define KC 184            // KK*NLAB
#define BLOCK 832         // 13 waves: 12 A-waves + light emission wave 12
#define NA 736            // 46 parents * 16 lanes
#define EMB 768           // emission wave start

typedef float v2f __attribute__((ext_vector_type(2)));

__device__ __forceinline__ float fastrcp(float x){ return __builtin_amdgcn_rcpf(x); }
__device__ __forceinline__ float flog2(float x){ return __builtin_amdgcn_logf(x); }
__device__ __forceinline__ float fmed3(float a, float b, float c){
    return __builtin_amdgcn_fmed3f(a, b, c);
}
template<int CTRL>
__device__ __forceinline__ float dppq(float v){   // quad_perm exchange (VALU pipe)
    return __uint_as_float((unsigned)__builtin_amdgcn_mov_dpp(
        (int)__float_as_uint(v), CTRL, 0xF, 0xF, false));
}
template<int OFF>
__device__ __forceinline__ float swz(float v){    // ds_swizzle xor (LDS pipe)
    return __uint_as_float((unsigned)__builtin_amdgcn_ds_swizzle(
        (int)__float_as_uint(v), OFF));
}
template<int N> struct IC { static constexpr int value = N; };

__global__ __launch_bounds__(BLOCK, 4) void lveg_kernel(
    const int* __restrict__ tokens,
    const float* __restrict__ s_w_tab,
    const float* __restrict__ s_m_tab,
    const float* __restrict__ s_v_tab,
    const float* __restrict__ t_weight,
    const float* __restrict__ t_mu,
    const float* __restrict__ t_var_p,
    float* __restrict__ out)
{
    // carry per child c: 12 floats = [lam0,lam1, glam0,glam1, z0,z1, lam2,lam3, glam2,glam3, z2,z3]
    // (z entries stored scaled by RLN2 for the selection key path)
    __shared__ v2f   pkc[2][NLAB][6];
    __shared__ float scv[KC];            // raw carry scores (final logsumexp)
    __shared__ float4 emi[2][NLAB];      // emission: sw, 1/sv, sm/sv, z2
    __shared__ int    tokL[LSEQ];
    __shared__ float4 tabA[NLAB*NLAB];   // per-(c,p): e0, e1, invDetS, l11
    __shared__ float2 tabB[NLAB*NLAB];   // per-(c,p): l01, A(=zeta1+LOG2PI+tw)

    const int b = blockIdx.x;
    const int tid = threadIdx.x;
    const int s = tid & 15;              // lane within 16-lane parent group
    const int p = tid >> 4;              // parent label 0..51
    const bool isA = (p < NLAB);
    const unsigned vmask2 = (s < 14) ? 0xFFFFFFFFu : 0u;       // ci=2 validity
    const unsigned vorm2  = (s < 14) ? 0u : 0xFF800000u;       // -inf for tail lanes
    const int c2 = (s < 14) ? (s + 32) : 0;                    // clamped ci=2 child
    const float NEGINF = __uint_as_float(0xFF800000u);

    // ---- one-time: phase-C constant tables into LDS + token preload ----
    for (int cp = tid; cp < NLAB*NLAB; cp += BLOCK) {
        float v0 = t_var_p[cp*3+0], v1 = t_var_p[cp*3+1], v2 = t_var_p[cp*3+2];
        float tm0 = t_mu[cp*2+0],  tm1 = t_mu[cp*2+1];
        float S00 = v0*v0 + v1*v1, S01 = v1*v2, S11 = v2*v2;
        float det = S00*S11 - S01*S01;
        float inv = 1.0f / det;
        float l00 = S11*inv, l01 = -S01*inv, l11 = S00*inv;
        float e0 = l00*tm0 + l01*tm1;
        float e1 = l01*tm0 + l11*tm1;
        float q1 = e0*(S00*e0 + S01*e1) + e1*(S01*e0 + S11*e1);
        float zeta1 = -0.5f*(2.0f*LOG2PI + __logf(det) + q1);
        tabA[cp] = make_float4(e0, e1, inv, l11);
        tabB[cp] = make_float2(l01, zeta1 + LOG2PI + t_weight[cp]);
    }
    for (int i = tid; i < LSEQ; i += BLOCK) tokL[i] = tokens[b*LSEQ + i];

    // ---- one-time: phase-A per-(c,p) constants in registers ----
    float rce0[3], rl11[3], rinv[3], rl11s[3], rqbs[3], rqes[3], rqcs[3], rAs[3];
    if (isA) {
#pragma unroll
        for (int ci = 0; ci < 3; ++ci) {
            int c = s + 16*ci;
            if (c < NLAB) {
                int cp = c*NLAB + p;
                float v0 = t_var_p[cp*3+0], v1 = t_var_p[cp*3+1], v2 = t_var_p[cp*3+2];
                float tm0 = t_mu[cp*2+0],  tm1 = t_mu[cp*2+1];
                float S00 = v0*v0 + v1*v1, S01 = v1*v2, S11 = v2*v2;
                float det = S00*S11 - S01*S01;
                float inv = 1.0f / det;
                float l00 = S11*inv, l01 = -S01*inv, l11 = S00*inv;
                float e0 = l00*tm0 + l01*tm1;
                float e1 = l01*tm0 + l11*tm1;
                float q1 = e0*(S00*e0 + S01*e1) + e1*(S01*e0 + S11*e1);
                float zeta1 = -0.5f*(2.0f*LOG2PI + __logf(det) + q1);
                rce0[ci]  = e0;
                rl11[ci]  = l11;
                rinv[ci]  = inv;
                rl11s[ci] = l11 * RLN2;
                rqbs[ci]  = 2.0f*l01*e1 * RLN2;
                rqes[ci]  = e1*e1 * RLN2;
                rqcs[ci]  = l00*e1*e1 * RLN2;
                rAs[ci]   = (zeta1 + LOG2PI + t_weight[cp]) * RLN2;
            } else {
                rce0[ci]=0.f; rl11[ci]=0.f; rinv[ci]=1.f; rl11s[ci]=0.f;
                rqbs[ci]=0.f; rqes[ci]=0.f; rqcs[ci]=0.f; rAs[ci]=0.f;
            }
        }
    }

    // ---- carry init from emission at position 0 ----
    if (tid < NLAB) {
        int tok0 = tokens[b * LSEQ];
        float sw  = s_w_tab[tok0*NLAB + tid];
        float sm  = s_m_tab[tok0*NLAB + tid];
        float svr = s_v_tab[tok0*NLAB + tid];
        float gv = svr*svr;
        float lam2 = 1.0f / gv;
        float glam = sm * lam2;
        float z2 = -0.5f*(LOG2PI + __logf(gv) + sm*glam);
        float zpad = (-1e30f - 0.5f*LOG2PI) * RLN2;
        v2f r;
        r.x = lam2; r.y = 1.0f;            pkc[0][tid][0] = r;
        r.x = glam; r.y = 0.0f;            pkc[0][tid][1] = r;
        r.x = (sw + z2)*RLN2; r.y = zpad;  pkc[0][tid][2] = r;
        r.x = 1.0f; r.y = 1.0f;            pkc[0][tid][3] = r;
        r.x = 0.0f; r.y = 0.0f;            pkc[0][tid][4] = r;
        r.x = zpad; r.y = zpad;            pkc[0][tid][5] = r;
    }
    // ---- emission prefetch for t=1 (dedicated wave 12) ----
    if (tid >= EMB) {
        int pe = tid - EMB;
        if (pe < NLAB) {
            int tok = tokens[b*LSEQ + 1];
            float sw  = s_w_tab[tok*NLAB + pe];
            float sm  = s_m_tab[tok*NLAB + pe];
            float svr = s_v_tab[tok*NLAB + pe];
            float sv = svr*svr;
            float rs = 1.0f / sv;
            float eb = sm * rs;
            float ez = -0.5f*(LOG2PI + __logf(sv) + sm*eb);
            emi[1][pe] = make_float4(sw, rs, eb, ez);
        }
    }
    __syncthreads();

    // ================= the scan: 1 barrier per step =================
    auto stepf = [&](auto CC, int t) {
        constexpr int CUR = decltype(CC)::value;
        if (isA) {
            // ---- upfront carry loads: 18 x ds_read_b64, pinned before compute ----
            const int cc[3] = {s, s + 16, c2};
            v2f q[3][6];
#pragma unroll
            for (int ci = 0; ci < 3; ++ci)
#pragma unroll
                for (int j = 0; j < 6; ++j)
                    q[ci][j] = pkc[CUR][cc[ci]][j];
            __builtin_amdgcn_sched_barrier(0);
            float t0=NEGINF, t1=NEGINF, t2=NEGINF, t3=NEGINF;
#define INS(kf, id, ci) {                                                     \
            unsigned kb = (__float_as_uint(kf) & 0xFFFFFF00u) | (unsigned)(id); \
            if ((ci) == 2) kb = (kb & vmask2) | vorm2;                        \
            float fk = __uint_as_float(kb);                                   \
            float n0 = fmaxf(t0, fk);                                         \
            float n1 = fmed3(fk, t0, t1);                                     \
            float n2 = fmed3(fk, t1, t2);                                     \
            float n3 = fmed3(fk, t2, t3);                                     \
            t0=n0; t1=n1; t2=n2; t3=n3; }
#define CANDP(ci, pr) {                                                       \
            v2f lamP  = q[ci][3*(pr)+0];                                      \
            v2f glamP = q[ci][3*(pr)+1];                                      \
            v2f zP    = q[ci][3*(pr)+2];                                      \
            v2f em0 = glamP + rce0[ci];                                       \
            v2f dm  = lamP * rl11[ci] + rinv[ci];                             \
            v2f tA  = em0 * rl11s[ci] - rqbs[ci];                             \
            v2f tB  = lamP * rqes[ci] + rqcs[ci];                             \
            v2f Q   = em0 * tA + tB;                                          \
            v2f rdm; rdm.x = fastrcp(dm.x); rdm.y = fastrcp(dm.y);            \
            v2f lg;  lg.x  = flog2(dm.x);   lg.y  = flog2(dm.y);              \
            v2f base  = zP + rAs[ci];                                         \
            v2f inner = Q * rdm - lg;                                         \
            v2f keyP  = 0.5f * inner + base;                                  \
            INS(keyP.x, (2*(pr))*NLAB   + s + 16*(ci), ci)                    \
            INS(keyP.y, (2*(pr)+1)*NLAB + s + 16*(ci), ci) }
            CANDP(0, 0) CANDP(0, 1)
            CANDP(1, 0) CANDP(1, 1)
            CANDP(2, 0) CANDP(2, 1)
#undef CANDP
#undef INS
            // ---- merge across 16-lane group: DPP (m=1,2) + swizzle (m=4,8) ----
#define MSTAGE(F) { float b0=F(t0), b1=F(t1), b2=F(t2), b3=F(t3);                 \
                float M0=fmaxf(t0,b3), M1=fmaxf(t1,b2), M2=fmaxf(t2,b1), M3=fmaxf(t3,b0); \
                float x;                                                          \
                x=fmaxf(M0,M2); M2=fminf(M0,M2); M0=x;  x=fmaxf(M1,M3); M3=fminf(M1,M3); M1=x; \
                x=fmaxf(M0,M1); M1=fminf(M0,M1); M0=x;  x=fmaxf(M2,M3); M3=fminf(M2,M3); M2=x; \
                t0=M0; t1=M1; t2=M2; t3=M3; }
            MSTAGE(dppq<0xB1>)      // xor 1
            MSTAGE(dppq<0x4E>)      // xor 2
            MSTAGE(swz<0x101F>)     // xor 4
            {   // final stage (xor 8): set-only
                float b0=swz<0x201F>(t0), b1=swz<0x201F>(t1),
                      b2=swz<0x201F>(t2), b3=swz<0x201F>(t3);
                float M0=fmaxf(t0,b3), M1=fmaxf(t1,b2), M2=fmaxf(t2,b1), M3=fmaxf(t3,b0);
                t0=M0; t1=M1; t2=M2; t3=M3;
            }
#undef MSTAGE
            // ---- phase C: lanes s<4 recompute survivor s exactly + emission ----
            if (s < 4) {
                float sel = (s==0)?t0 : (s==1)?t1 : (s==2)?t2 : t3;
                unsigned kc = __float_as_uint(sel) & 0xFFu;
                unsigned k  = (kc * 1428u) >> 16;
                int c  = (int)kc - (int)k*NLAB;
                int cp = c*NLAB + p;
                float4 ta = tabA[cp];                 // e0,e1,inv,l11
                float2 tb = tabB[cp];                 // l01, A
                const float* sp = (const float*)&pkc[CUR][c][0]
                                  + 6*(int)(k >> 1) + (int)(k & 1);
                float lam2 = sp[0];
                float glam = sp[2];
                float z2s  = sp[4] * LN2;
                float em0 = ta.x + glam;
                float em1 = ta.y;
                float l01 = tb.x;
                float l00 = fmaf(l01, l01, ta.z) * fastrcp(ta.w);  // (inv+l01^2)/l11
                float dm  = fmaf(lam2, ta.w, ta.z);
                float rdm = fastrcp(dm);
                float lm00 = l00 + lam2;
                float Q = fmaf(em0, fmaf(ta.w, em0, -2.0f*l01*em1), lm00*em1*em1);
                float score = fmaf(0.5f, fmaf(Q, rdm, -__logf(dm)), tb.y + z2s);
                float mu2  = rdm*(lm00*em1 - l01*em0);
                float var2 = lm00*rdm;
                float4 ev = emi[CUR ^ 1][p];
                float rv1 = fastrcp(var2);
                float lam = rv1 + ev.y;
                float emm = fmaf(mu2, rv1, ev.z);
                float vm  = fastrcp(lam);
                float z1 = -0.5f*(LOG2PI + __logf(var2) + mu2*mu2*rv1);
                float zm = -0.5f*(LOG2PI + __logf(vm) + emm*emm*vm);
                float nsc = score + (z1 + ev.w - zm) + ev.x;
                float* wp = (float*)&pkc[CUR ^ 1][p][0] + 6*(s >> 1) + (s & 1);
                wp[0] = lam;
                wp[2] = emm;
                wp[4] = (nsc + zm) * RLN2;
                scv[s*NLAB + p] = nsc;
            }
        } else if (tid >= EMB) {
            // ---- emission prefetch for step t+1 into emi[CUR] (wave 12) ----
            int pe = tid - EMB;
            if (pe < NLAB && t + 1 < LSEQ) {
                int tok = tokL[t + 1];
                float sw  = s_w_tab[tok*NLAB + pe];
                float sm  = s_m_tab[tok*NLAB + pe];
                float svr = s_v_tab[tok*NLAB + pe];
                float sv = svr*svr;
                float rs = 1.0f / sv;
                float eb = sm * rs;
                float ez = -0.5f*(LOG2PI + __logf(sv) + sm*eb);
                emi[CUR][pe] = make_float4(sw, rs, eb, ez);
            }
        }
        __syncthreads();   // the ONLY barrier per step
    };

    int t = 1;
#pragma unroll 1
    for (int it = 0; it < (LSEQ - 2) / 2; ++it) {   // 255 double-steps: t=1..510
        stepf(IC<0>{}, t); ++t;
        stepf(IC<1>{}, t); ++t;
    }
    stepf(IC<0>{}, t);   // t = 511

    // ---- final logsumexp over 184 component scores (wave 0) ----
    if (tid < 64) {
        float mx = -1e38f;
        for (int i = tid; i < KC; i += 64) mx = fmaxf(mx, scv[i]);
#pragma unroll
        for (int m = 32; m; m >>= 1) mx = fmaxf(mx, __shfl_xor(mx, m, 64));
        float sum = 0.0f;
        for (int i = tid; i < KC; i += 64) sum += __expf(scv[i] - mx);
#pragma unroll
        for (int m = 32; m; m >>= 1) sum += __shfl_xor(sum, m, 64);
        if (tid == 0) out[b] = mx + __logf(sum);
    }
}

extern "C" void kernel_launch(void* const* d_in, const int* in_sizes, int n_in,
                              void* d_out, int out_size, void* d_ws, size_t ws_size,
                              hipStream_t stream) {
    const int*   tokens = (const int*)d_in[0];
    const float* sw     = (const float*)d_in[1];
    const float* sm     = (const float*)d_in[2];
    const float* sv     = (const float*)d_in[3];
    const float* tw     = (const float*)d_in[4];
    const float* tmu    = (const float*)d_in[5];
    const float* tvp    = (const float*)d_in[6];
    float* o = (float*)d_out;
    hipLaunchKernelGGL(lveg_kernel, dim3(64), dim3(BLOCK), 0, stream,
                       tokens, sw, sm, sv, tw, tmu, tvp, o);
}